// Round 5
// baseline (485.681 us; speedup 1.0000x reference)
//
#include <hip/hip_runtime.h>
#include <cstdint>
#include <cstddef>

#define B_   4096
#define T_   128
#define IN_  768
#define H_   256
#define BM_  256          // batch rows per workgroup
#define KC1  (IN_ / 32)   // 24 k-chunks, layer 1 (BK=32)
#define NC2  16           // 16 k-chunks, layer 2 (BK=16)

typedef __bf16 bf16_t;
typedef bf16_t bf16x8 __attribute__((ext_vector_type(8)));
typedef bf16_t bf16x4 __attribute__((ext_vector_type(4)));
typedef float  floatx16 __attribute__((ext_vector_type(16)));

#define MFMA32(a, b, c) __builtin_amdgcn_mfma_f32_32x32x16_bf16((a), (b), (c), 0, 0, 0)

__device__ __forceinline__ void gl_lds16(const bf16_t* g, bf16_t* l) {
    __builtin_amdgcn_global_load_lds(
        (const __attribute__((address_space(1))) void*)g,
        (__attribute__((address_space(3))) void*)l, 16, 0, 0);
}

// fine-grained wait: block until <= N vmem ops outstanding (in-order retirement
// => everything older than the newest N has landed in LDS)
template <int N>
__device__ __forceinline__ void vmwait() {
    asm volatile("s_waitcnt vmcnt(%0)" :: "i"(N) : "memory");
}
// raw barrier WITHOUT __syncthreads()'s vmcnt(0) drain
__device__ __forceinline__ void wg_barrier() {
    asm volatile("" ::: "memory");
    __builtin_amdgcn_s_barrier();
    asm volatile("" ::: "memory");
}

// ---------------- single fused transform kernel ----------------
// blocks [0,3072):      W1 [t][768][256] fp32 -> [t][kc24][kq4][h256][8k] bf16
// blocks [3072,4096):   W2 [t][256][256] fp32 -> [t][kc8][kq4][h256][8k]  bf16
// blocks [4096,4864):   x  [4096][768]  fp32 -> [mb32][kc24][kq4][m128][8k] bf16
__global__ __launch_bounds__(256)
void tile_all(const float* __restrict__ x, const float* __restrict__ W1,
              const float* __restrict__ W2, bf16_t* __restrict__ xt,
              bf16_t* __restrict__ w1t, bf16_t* __restrict__ w2t) {
    const int b   = blockIdx.x;
    const int tid = threadIdx.x;
    if (b < T_ * KC1 + T_ * 8) {
        const float* src; bf16_t* dst; int t, kc, K, KC;
        if (b < T_ * KC1) { t = b / KC1; kc = b - t * KC1; K = IN_; KC = KC1; src = W1; dst = w1t; }
        else { int bb = b - T_ * KC1; t = bb >> 3; kc = bb & 7; K = H_; KC = 8; src = W2; dst = w2t; }
        const int kq = tid >> 6, h4 = (tid & 63) * 4;
        const float* s = src + ((size_t)t * K + kc * 32 + kq * 8) * H_ + h4;
        float r[8][4];
#pragma unroll
        for (int e = 0; e < 8; ++e) {
            float4 v = *(const float4*)(s + (size_t)e * H_);
            r[e][0] = v.x; r[e][1] = v.y; r[e][2] = v.z; r[e][3] = v.w;
        }
        bf16_t* d = dst + (((size_t)(t * KC + kc) * 4 + kq) * H_ + h4) * 8;
#pragma unroll
        for (int c = 0; c < 4; ++c) {
            bf16x8 v;
#pragma unroll
            for (int e = 0; e < 8; ++e) v[e] = (bf16_t)r[e][c];
            *(bf16x8*)(d + c * 8) = v;
        }
    } else {
        const int bb = b - (T_ * KC1 + T_ * 8);
        const int mb = bb / KC1, kc = bb - mb * KC1;
        const int r = tid >> 3, c = tid & 7;   // 32 rows x 8 float4-cols per pass
#pragma unroll
        for (int it = 0; it < 4; ++it) {
            const int m = it * 32 + r;
            float4 v = *(const float4*)(x + ((size_t)(mb * 128 + m)) * IN_ + kc * 32 + c * 4);
            bf16x4 o; o[0] = (bf16_t)v.x; o[1] = (bf16_t)v.y; o[2] = (bf16_t)v.z; o[3] = (bf16_t)v.w;
            *(bf16x4*)(xt + ((size_t)(mb * KC1 + kc) * 4 + (c >> 1)) * 1024 + m * 8 + (c & 1) * 4) = o;
        }
    }
}

// ---------------- fused per-task MLP, software-pipelined K-loops ----------------
// h^T = W^T x^T so MFMA C/D cols = batch rows; epilogue packs reg-quads (4
// contiguous h) into hbuf [blk=h/8][m=256][8h] == next layer's B-frag pattern.
// Layer-1: ring-4 x 32KB slots (inside hbuf), prefetch distance 3, one raw
// barrier + vmcnt(8) per chunk. Layer-2: ring-3 x 8KB, distance 2, vmcnt(1).
// Steady state never drains vmcnt to 0.
__global__ __launch_bounds__(512, 1)
void mtmlp_fused5(const bf16_t* __restrict__ xt, const bf16_t* __restrict__ w1t,
                  const float* __restrict__ b1, const bf16_t* __restrict__ w2t,
                  const float* __restrict__ b2, const float* __restrict__ W3,
                  const float* __restrict__ b3, float* __restrict__ out) {
    // XCD swizzle: consecutive ids round-robin over 8 XCDs; XCD k owns tasks
    // [16k,16k+16) so W1[t]/W2[t] stay L2-resident per XCD.
    const int L    = blockIdx.x;
    const int xcd  = L & 7;
    const int slot = L >> 3;
    const int t    = xcd * 16 + (slot >> 4);
    const int mblk = slot & 15;
    const int m0   = mblk * BM_;
    const int mb0  = mblk * 2;

    const int tid  = threadIdx.x;
    const int lane = tid & 63;
    const int wid  = tid >> 6;
    const int wm   = wid >> 2;            // h half (128)
    const int wn   = wid & 3;             // m quarter (64)
    const int ln31 = lane & 31;
    const int hi   = lane >> 5;

    __shared__ __align__(16) bf16_t hbuf[BM_ * H_];      // 128 KB; ring-4 slots in layer 1
    __shared__ __align__(16) bf16_t wt2[3 * 4096];       // 24 KB: ring-3 for layer 2; w3s alias
    float* w3s = (float*)wt2;

    floatx16 acc[4][2];
#pragma unroll
    for (int i = 0; i < 4; ++i)
#pragma unroll
        for (int j = 0; j < 2; ++j)
#pragma unroll
            for (int e = 0; e < 16; ++e) acc[i][j][e] = 0.0f;

    // ---------------- layer 1 ----------------
    const bf16_t* w1base = w1t + (size_t)t * KC1 * 8192;
    const bf16_t* x0base = xt + (size_t)mb0 * KC1 * 4096;
    const bf16_t* x1base = xt + (size_t)(mb0 + 1) * KC1 * 4096;

    auto stage1 = [&](int sl, int kc) {   // slot: [W 16KB][x0 8KB][x1 8KB]; 4 instr/wave
        bf16_t* buf = hbuf + sl * 16384;
        const bf16_t* ws = w1base + (size_t)kc * 8192;
        gl_lds16(ws + tid * 8,        buf + tid * 8);
        gl_lds16(ws + 4096 + tid * 8, buf + 4096 + tid * 8);
        gl_lds16(x0base + (size_t)kc * 4096 + tid * 8, buf + 8192 + tid * 8);
        gl_lds16(x1base + (size_t)kc * 4096 + tid * 8, buf + 12288 + tid * 8);
    };
    auto comp1 = [&](int sl) {
        const bf16_t* buf = hbuf + sl * 16384;
#pragma unroll
        for (int s = 0; s < 2; ++s) {
            const int kq = s * 2 + hi;
            bf16x8 A[4], Bf[2];
#pragma unroll
            for (int i = 0; i < 4; ++i)
                A[i] = *(const bf16x8*)(buf + (size_t)(kq * H_ + wm * 128 + i * 32 + ln31) * 8);
#pragma unroll
            for (int j = 0; j < 2; ++j) {
                const int mm = wn * 64 + j * 32 + ln31;
                Bf[j] = *(const bf16x8*)(buf + 8192 + (mm >> 7) * 4096 +
                                         (size_t)(kq * 128 + (mm & 127)) * 8);
            }
#pragma unroll
            for (int i = 0; i < 4; ++i)
#pragma unroll
                for (int j = 0; j < 2; ++j) acc[i][j] = MFMA32(A[i], Bf[j], acc[i][j]);
        }
    };

    stage1(0, 0); stage1(1, 1); stage1(2, 2);        // 12 loads in flight
    for (int kc = 0; kc <= KC1 - 4; ++kc) {          // kc = 0..20
        vmwait<8>();                                 // chunk kc landed (>=12 newer ops behind it)
        wg_barrier();                                // all waves' chunk-kc data visible
        stage1((kc + 3) & 3, kc + 3);                // overwrites slot read at kc-1: safe post-barrier
        comp1(kc & 3);
    }
    vmwait<8>(); wg_barrier(); comp1((KC1 - 3) & 3); // kc=21: {21,22,23} in flight
    vmwait<4>(); wg_barrier(); comp1((KC1 - 2) & 3); // kc=22
    vmwait<0>(); wg_barrier(); comp1((KC1 - 1) & 3); // kc=23

    __syncthreads();   // all waves done with ring reads (vmcnt already 0: free drain)

    // prefetch layer-2 chunks 0,1 (8KB each); epilogue-1 hides their latency
    const bf16_t* w2base = w2t + (size_t)t * 32 * 2048;   // [kq32][256][8]
    auto stage2 = [&](int sl, int c) {                    // 1 instr/wave
        gl_lds16(w2base + (size_t)c * 4096 + tid * 8, wt2 + sl * 4096 + tid * 8);
    };
    stage2(0, 0); stage2(1, 1);

    // epilogue 1: bias + relu -> hbuf [blk][m][8]
#pragma unroll
    for (int i = 0; i < 4; ++i) {
#pragma unroll
        for (int g = 0; g < 4; ++g) {
            const int h0 = wm * 128 + i * 32 + g * 8 + 4 * hi;
            float4 bias = *(const float4*)(b1 + t * H_ + h0);
            const int blk = h0 >> 3;
#pragma unroll
            for (int j = 0; j < 2; ++j) {
                const int mm = wn * 64 + j * 32 + ln31;
                bf16x4 o;
                o[0] = (bf16_t)fmaxf(acc[i][j][4 * g + 0] + bias.x, 0.0f);
                o[1] = (bf16_t)fmaxf(acc[i][j][4 * g + 1] + bias.y, 0.0f);
                o[2] = (bf16_t)fmaxf(acc[i][j][4 * g + 2] + bias.z, 0.0f);
                o[3] = (bf16_t)fmaxf(acc[i][j][4 * g + 3] + bias.w, 0.0f);
                *(bf16x4*)(hbuf + (size_t)(blk * BM_ + mm) * 8 + 4 * hi) = o;
            }
        }
    }

#pragma unroll
    for (int i = 0; i < 4; ++i)
#pragma unroll
        for (int j = 0; j < 2; ++j)
#pragma unroll
            for (int e = 0; e < 16; ++e) acc[i][j][e] = 0.0f;

    __syncthreads();   // h1 visible to all waves (drains stage2(0,1): once, acceptable)

    // ---------------- layer 2: 16 chunks of BK=16, ring-3, distance 2 ----------------
    // chunk c lives in slot c%3. (R4 bug: stage counter wrapped at 2, re-staging
    // chunks 0,1,2 forever — now chunk index and slot index are kept separate.)
    auto comp2 = [&](int sl, int c) {
        const bf16_t* buf = wt2 + sl * 4096;   // [kql=2][256][8]
        bf16x8 A[4], Bf[2];
#pragma unroll
        for (int i = 0; i < 4; ++i)
            A[i] = *(const bf16x8*)(buf + (size_t)(hi * H_ + wm * 128 + i * 32 + ln31) * 8);
        const int blk = c * 2 + hi;
#pragma unroll
        for (int j = 0; j < 2; ++j) {
            const int mm = wn * 64 + j * 32 + ln31;
            Bf[j] = *(const bf16x8*)(hbuf + (size_t)(blk * BM_ + mm) * 8);
        }
#pragma unroll
        for (int i = 0; i < 4; ++i)
#pragma unroll
            for (int j = 0; j < 2; ++j) acc[i][j] = MFMA32(A[i], Bf[j], acc[i][j]);
    };

    {
        int sl = 0, sp = 2;                       // slot of chunk c; slot of chunk c+2
        for (int c = 0; c <= NC2 - 3; ++c) {      // c = 0..13
            vmwait<1>();                           // chunk c landed
            wg_barrier();
            stage2(sp, c + 2);                     // slot (c+2)%3: read at c-1, safe post-barrier
            comp2(sl, c);
            sl = (sl == 2) ? 0 : sl + 1;
            sp = (sp == 2) ? 0 : sp + 1;
        }
    }
    vmwait<1>(); wg_barrier(); comp2((NC2 - 2) % 3, NC2 - 2);   // c=14 (slot 2)
    vmwait<0>(); wg_barrier(); comp2((NC2 - 1) % 3, NC2 - 1);   // c=15 (slot 0)

    __syncthreads();   // all waves done reading hbuf/wt2 (vmcnt already 0)

    // epilogue 2: bias + relu -> h2 in hbuf (same layout); stage W3 into w3s
    if (tid < H_) w3s[tid] = W3[t * H_ + tid];
#pragma unroll
    for (int i = 0; i < 4; ++i) {
#pragma unroll
        for (int g = 0; g < 4; ++g) {
            const int h0 = wm * 128 + i * 32 + g * 8 + 4 * hi;
            float4 bias = *(const float4*)(b2 + t * H_ + h0);
            const int blk = h0 >> 3;
#pragma unroll
            for (int j = 0; j < 2; ++j) {
                const int mm = wn * 64 + j * 32 + ln31;
                bf16x4 o;
                o[0] = (bf16_t)fmaxf(acc[i][j][4 * g + 0] + bias.x, 0.0f);
                o[1] = (bf16_t)fmaxf(acc[i][j][4 * g + 1] + bias.y, 0.0f);
                o[2] = (bf16_t)fmaxf(acc[i][j][4 * g + 2] + bias.z, 0.0f);
                o[3] = (bf16_t)fmaxf(acc[i][j][4 * g + 3] + bias.w, 0.0f);
                *(bf16x4*)(hbuf + (size_t)(blk * BM_ + mm) * 8 + 4 * hi) = o;
            }
        }
    }
    __syncthreads();

    // ---------------- layer 3 ----------------
    {
        const int m = tid >> 1, seg = tid & 1;
        float sum = 0.0f;
#pragma unroll
        for (int b = 0; b < 16; ++b) {
            const int blk = seg * 16 + b;
            const bf16x8 v = *(const bf16x8*)(hbuf + (size_t)(blk * BM_ + m) * 8);
            const float* w = w3s + blk * 8;
#pragma unroll
            for (int e = 0; e < 8; ++e) sum += (float)v[e] * w[e];
        }
        sum += __shfl_xor(sum, 1);
        if (seg == 0) out[(size_t)(m0 + m) * T_ + t] = sum + b3[t];
    }
}

extern "C" void kernel_launch(void* const* d_in, const int* in_sizes, int n_in,
                              void* d_out, int out_size, void* d_ws, size_t ws_size,
                              hipStream_t stream) {
    const float* x  = (const float*)d_in[0];
    const float* W1 = (const float*)d_in[1];
    const float* b1 = (const float*)d_in[2];
    const float* W2 = (const float*)d_in[3];
    const float* b2 = (const float*)d_in[4];
    const float* W3 = (const float*)d_in[5];
    const float* b3 = (const float*)d_in[6];
    float* out = (float*)d_out;

    const size_t nx  = (size_t)B_ * IN_;
    const size_t nw1 = (size_t)T_ * IN_ * H_;

    bf16_t* xt  = (bf16_t*)d_ws;
    bf16_t* w1t = xt + nx;
    bf16_t* w2t = w1t + nw1;

    tile_all<<<dim3(T_ * KC1 + T_ * 8 + 32 * KC1), 256, 0, stream>>>(x, W1, W2, xt, w1t, w2t);
    mtmlp_fused5<<<dim3(2048), 512, 0, stream>>>(xt, w1t, b1, w2t, b2, W3, b3, out);
}

// Round 6
// 474.796 us; speedup vs baseline: 1.0229x; 1.0229x over previous
//
#include <hip/hip_runtime.h>
#include <cstdint>
#include <cstddef>

#define B_   4096
#define T_   128
#define IN_  768
#define H_   256
#define BM_  128          // batch rows per workgroup
#define KC1  (IN_ / 32)   // 24 32k-chunks (transform granularity)
#define NS1  48           // layer-1 k16 steps
#define NS2  16           // layer-2 k16 steps

typedef __bf16 bf16_t;
typedef bf16_t bf16x8 __attribute__((ext_vector_type(8)));
typedef bf16_t bf16x4 __attribute__((ext_vector_type(4)));
typedef float  floatx16 __attribute__((ext_vector_type(16)));

#define MFMA32(a, b, c) __builtin_amdgcn_mfma_f32_32x32x16_bf16((a), (b), (c), 0, 0, 0)

__device__ __forceinline__ void lgkm0_barrier() {
    asm volatile("s_waitcnt lgkmcnt(0)" ::: "memory");
    __builtin_amdgcn_s_barrier();
    asm volatile("" ::: "memory");
}

// ---------------- transform kernel (unchanged from R5; layouts proven) ----------------
// blocks [0,3072):      W1 [t][768][256] fp32 -> [t][kc24][kq4][h256][8k] bf16
// blocks [3072,4096):   W2 [t][256][256] fp32 -> [t][kc8][kq4][h256][8k]  bf16
// blocks [4096,4864):   x  [4096][768]  fp32 -> [mb32][kc24][kq4][m128][8k] bf16
__global__ __launch_bounds__(256)
void tile_all(const float* __restrict__ x, const float* __restrict__ W1,
              const float* __restrict__ W2, bf16_t* __restrict__ xt,
              bf16_t* __restrict__ w1t, bf16_t* __restrict__ w2t) {
    const int b   = blockIdx.x;
    const int tid = threadIdx.x;
    if (b < T_ * KC1 + T_ * 8) {
        const float* src; bf16_t* dst; int t, kc, K, KC;
        if (b < T_ * KC1) { t = b / KC1; kc = b - t * KC1; K = IN_; KC = KC1; src = W1; dst = w1t; }
        else { int bb = b - T_ * KC1; t = bb >> 3; kc = bb & 7; K = H_; KC = 8; src = W2; dst = w2t; }
        const int kq = tid >> 6, h4 = (tid & 63) * 4;
        const float* s = src + ((size_t)t * K + kc * 32 + kq * 8) * H_ + h4;
        float r[8][4];
#pragma unroll
        for (int e = 0; e < 8; ++e) {
            float4 v = *(const float4*)(s + (size_t)e * H_);
            r[e][0] = v.x; r[e][1] = v.y; r[e][2] = v.z; r[e][3] = v.w;
        }
        bf16_t* d = dst + (((size_t)(t * KC + kc) * 4 + kq) * H_ + h4) * 8;
#pragma unroll
        for (int c = 0; c < 4; ++c) {
            bf16x8 v;
#pragma unroll
            for (int e = 0; e < 8; ++e) v[e] = (bf16_t)r[e][c];
            *(bf16x8*)(d + c * 8) = v;
        }
    } else {
        const int bb = b - (T_ * KC1 + T_ * 8);
        const int mb = bb / KC1, kc = bb - mb * KC1;
        const int r = tid >> 3, c = tid & 7;
#pragma unroll
        for (int it = 0; it < 4; ++it) {
            const int m = it * 32 + r;
            float4 v = *(const float4*)(x + ((size_t)(mb * 128 + m)) * IN_ + kc * 32 + c * 4);
            bf16x4 o; o[0] = (bf16_t)v.x; o[1] = (bf16_t)v.y; o[2] = (bf16_t)v.z; o[3] = (bf16_t)v.w;
            *(bf16x4*)(xt + ((size_t)(mb * KC1 + kc) * 4 + (c >> 1)) * 1024 + m * 8 + (c & 1) * 4) = o;
        }
    }
}

// ---------------- fused MLP: register staging, 2 WG/CU, x direct-to-reg ----------------
// h^T = W^T x^T (C/D col = batch row). W chunks: global->VGPR->ds_write into a
// ring-2 of 8KB slots; barriers are raw s_barrier + lgkmcnt(0) only — in-flight
// global loads (VGPR dest) cross barriers freely; compiler inserts vmcnt(N)
// before each dependent ds_write / MFMA. x B-frags: direct global->VGPR from the
// tiled image (512B-coalesced per 32-lane group), prefetched 1 step ahead.
__global__ __launch_bounds__(256, 2)
void mtmlp_fused6(const bf16_t* __restrict__ xt, const bf16_t* __restrict__ w1t,
                  const float* __restrict__ b1, const bf16_t* __restrict__ w2t,
                  const float* __restrict__ b2, const float* __restrict__ W3,
                  const float* __restrict__ b3, float* __restrict__ out) {
    // XCD swizzle: XCD k owns tasks [16k,16k+16) -> W[t] L2-resident per XCD.
    const int L    = blockIdx.x;              // 0..4095
    const int xcd  = L & 7;
    const int idx  = L >> 3;                  // 0..511
    const int t    = xcd * 16 + (idx >> 5);
    const int mblk = idx & 31;
    const int m0   = mblk * BM_;

    const int tid  = threadIdx.x;
    const int lane = tid & 63;
    const int wid  = tid >> 6;                // 0..3
    const int wm   = wid & 1;                 // h half (128)
    const int wn   = wid >> 1;                // m half (64)
    const int ln31 = lane & 31;
    const int hi   = lane >> 5;

    __shared__ __align__(16) bf16_t hbuf[BM_ * H_];   // 64 KB
    __shared__ __align__(16) bf16_t wring[2 * 4096];  // 16 KB: ring-2 W slots; w3s alias
    float* w3s = (float*)wring;                       // slot0 alias, used in layer 3

    floatx16 acc[2][2];
#pragma unroll
    for (int i = 0; i < 2; ++i)
#pragma unroll
        for (int j = 0; j < 2; ++j)
#pragma unroll
            for (int e = 0; e < 16; ++e) acc[i][j][e] = 0.0f;
    floatx16 acc2[2][2];
#pragma unroll
    for (int i = 0; i < 2; ++i)
#pragma unroll
        for (int j = 0; j < 2; ++j)
#pragma unroll
            for (int e = 0; e < 16; ++e) acc2[i][j][e] = 0.0f;
    // NOTE: wave tile is 4(i)x2(j) 32-blocks; acc split as acc[2][2]+acc2[2][2]
    // purely to keep array indexing simple: i-blocks 0,1 in acc, 2,3 in acc2.

    const bf16_t* w1base = w1t + (size_t)t * NS1 * 4096;   // step image = 4096 elems (8KB)
    const bf16_t* w2base = w2t + (size_t)t * NS2 * 4096;
    const bf16_t* xbase  = xt + (size_t)mblk * KC1 * 4096;
    const int woff = tid * 16;                             // staging: 32B per thread
    const int xoff = (wn * 64 + ln31) * 8;

    bf16x8 wrA[2], wrB[2], xcur[2], xnxt[2];

    auto loadW = [&](bf16x8* r, const bf16_t* base, int c) {
        const bf16_t* p = base + (size_t)c * 4096 + woff;
        r[0] = *(const bf16x8*)(p);
        r[1] = *(const bf16x8*)(p + 8);
    };
    auto writeW = [&](const bf16x8* r, int sl) {
        bf16_t* p = wring + sl * 4096 + woff;
        *(bf16x8*)(p)     = r[0];
        *(bf16x8*)(p + 8) = r[1];
    };
    auto loadX = [&](bf16x8* r, int c) {   // x B-frags for step c, both j
        const bf16_t* p = xbase + ((size_t)((c >> 1) * 4 + (c & 1) * 2 + hi)) * 1024 + xoff;
        r[0] = *(const bf16x8*)(p);
        r[1] = *(const bf16x8*)(p + 256);  // j=1: +32 rows * 8
    };
    auto comp = [&](const bf16x8* xf, int sl) {
        const bf16_t* buf = wring + sl * 4096;   // [kq2][h256][8k]
        bf16x8 A0 = *(const bf16x8*)(buf + (size_t)(hi * 256 + wm * 128 + 0 * 32 + ln31) * 8);
        bf16x8 A1 = *(const bf16x8*)(buf + (size_t)(hi * 256 + wm * 128 + 1 * 32 + ln31) * 8);
        bf16x8 A2 = *(const bf16x8*)(buf + (size_t)(hi * 256 + wm * 128 + 2 * 32 + ln31) * 8);
        bf16x8 A3 = *(const bf16x8*)(buf + (size_t)(hi * 256 + wm * 128 + 3 * 32 + ln31) * 8);
#pragma unroll
        for (int j = 0; j < 2; ++j) {
            acc[0][j]  = MFMA32(A0, xf[j], acc[0][j]);
            acc[1][j]  = MFMA32(A1, xf[j], acc[1][j]);
            acc2[0][j] = MFMA32(A2, xf[j], acc2[0][j]);
            acc2[1][j] = MFMA32(A3, xf[j], acc2[1][j]);
        }
    };

    // ---------------- layer 1: 48 k16-steps, ring-2, register-staged ----------------
    loadW(wrA, w1base, 0); loadW(wrB, w1base, 1); loadX(xcur, 0);
    writeW(wrA, 0);
    lgkm0_barrier();                       // slot0 = step0 visible

    for (int c = 0; c < NS1 - 2; c += 2) { // c = 0..44
        writeW(wrB, 1);                    // step c+1 -> slot1 (readers of slot1 past last barrier)
        loadW(wrA, w1base, c + 2);
        loadX(xnxt, c + 1);
        comp(xcur, 0);                     // step c from slot0
        lgkm0_barrier();
        writeW(wrA, 0);                    // step c+2 -> slot0 (comp(c) readers done)
        loadW(wrB, w1base, c + 3);         // c+3 <= 47
        loadX(xcur, c + 2);
        comp(xnxt, 1);                     // step c+1 from slot1
        lgkm0_barrier();
    }
    // peel c=46: slot0=46, wrB=47, xcur=46
    writeW(wrB, 1);
    loadX(xnxt, 47);
    loadW(wrA, w2base, 0);                 // prefetch layer-2 steps 0,1 early
    loadW(wrB, w2base, 1);
    comp(xcur, 0);
    lgkm0_barrier();
    comp(xnxt, 1);                         // peel c=47

    // epilogue 1: bias + relu -> hbuf [blk=h/8][m=128][8h]
    {
        const floatx16* accp[4] = {&acc[0][0], nullptr, nullptr, nullptr};
#pragma unroll
        for (int i = 0; i < 4; ++i) {
            const floatx16* a0 = (i < 2) ? &acc[i][0] : &acc2[i - 2][0];
#pragma unroll
            for (int g = 0; g < 4; ++g) {
                const int h0 = wm * 128 + i * 32 + g * 8 + 4 * hi;
                float4 bias = *(const float4*)(b1 + t * H_ + h0);
                const int blk = h0 >> 3;
#pragma unroll
                for (int j = 0; j < 2; ++j) {
                    const int mm = wn * 64 + j * 32 + ln31;
                    const floatx16& a = a0[j];
                    bf16x4 o;
                    o[0] = (bf16_t)fmaxf(a[4 * g + 0] + bias.x, 0.0f);
                    o[1] = (bf16_t)fmaxf(a[4 * g + 1] + bias.y, 0.0f);
                    o[2] = (bf16_t)fmaxf(a[4 * g + 2] + bias.z, 0.0f);
                    o[3] = (bf16_t)fmaxf(a[4 * g + 3] + bias.w, 0.0f);
                    *(bf16x4*)(hbuf + (size_t)(blk * BM_ + mm) * 8 + 4 * hi) = o;
                }
            }
        }
        (void)accp;
    }
#pragma unroll
    for (int i = 0; i < 2; ++i)
#pragma unroll
        for (int j = 0; j < 2; ++j)
#pragma unroll
            for (int e = 0; e < 16; ++e) { acc[i][j][e] = 0.0f; acc2[i][j][e] = 0.0f; }

    writeW(wrA, 0);                        // W2 step0 -> slot0 (slot0 readers = comp(46), done)
    lgkm0_barrier();                       // publishes h1 stores + W2 slot0

    // ---------------- layer 2: 16 k16-steps, B-frags from hbuf ----------------
    auto comp2 = [&](int c, int sl) {
        bf16x8 Bf[2];
        const int blk = c * 2 + hi;
#pragma unroll
        for (int j = 0; j < 2; ++j) {
            const int mm = wn * 64 + j * 32 + ln31;
            Bf[j] = *(const bf16x8*)(hbuf + (size_t)(blk * BM_ + mm) * 8);
        }
        comp(Bf, sl);
    };

    for (int c = 0; c < NS2 - 2; c += 2) { // c = 0..12
        writeW(wrB, 1);
        loadW(wrA, w2base, c + 2);
        comp2(c, 0);
        lgkm0_barrier();
        writeW(wrA, 0);
        loadW(wrB, w2base, c + 3);         // c+3 <= 15
        comp2(c + 1, 1);
        lgkm0_barrier();
    }
    // peel c=14: slot0=14, wrB=15
    writeW(wrB, 1);
    comp2(14, 0);
    lgkm0_barrier();
    if (tid < H_) w3s[tid] = W3[t * H_ + tid];   // slot0 free (comp2(14) done + barrier)
    comp2(15, 1);
    lgkm0_barrier();                       // w3s visible; all hbuf reads done

    // epilogue 2: bias + relu -> h2 in hbuf (same layout)
#pragma unroll
    for (int i = 0; i < 4; ++i) {
        const floatx16* a0 = (i < 2) ? &acc[i][0] : &acc2[i - 2][0];
#pragma unroll
        for (int g = 0; g < 4; ++g) {
            const int h0 = wm * 128 + i * 32 + g * 8 + 4 * hi;
            float4 bias = *(const float4*)(b2 + t * H_ + h0);
            const int blk = h0 >> 3;
#pragma unroll
            for (int j = 0; j < 2; ++j) {
                const int mm = wn * 64 + j * 32 + ln31;
                const floatx16& a = a0[j];
                bf16x4 o;
                o[0] = (bf16_t)fmaxf(a[4 * g + 0] + bias.x, 0.0f);
                o[1] = (bf16_t)fmaxf(a[4 * g + 1] + bias.y, 0.0f);
                o[2] = (bf16_t)fmaxf(a[4 * g + 2] + bias.z, 0.0f);
                o[3] = (bf16_t)fmaxf(a[4 * g + 3] + bias.w, 0.0f);
                *(bf16x4*)(hbuf + (size_t)(blk * BM_ + mm) * 8 + 4 * hi) = o;
            }
        }
    }
    lgkm0_barrier();

    // ---------------- layer 3: out[m,t] = h2[m,:]·W3 + b3[t] ----------------
    {
        const int m = tid >> 1, seg = tid & 1;   // 2 threads/row, 128 h each
        float sum = 0.0f;
#pragma unroll
        for (int b = 0; b < 16; ++b) {
            const int blk = seg * 16 + b;
            const bf16x8 v = *(const bf16x8*)(hbuf + (size_t)(blk * BM_ + m) * 8);
            const float* w = w3s + blk * 8;
#pragma unroll
            for (int e = 0; e < 8; ++e) sum += (float)v[e] * w[e];
        }
        sum += __shfl_xor(sum, 1);
        if (seg == 0) out[(size_t)(m0 + m) * T_ + t] = sum + b3[t];
    }
}

extern "C" void kernel_launch(void* const* d_in, const int* in_sizes, int n_in,
                              void* d_out, int out_size, void* d_ws, size_t ws_size,
                              hipStream_t stream) {
    const float* x  = (const float*)d_in[0];
    const float* W1 = (const float*)d_in[1];
    const float* b1 = (const float*)d_in[2];
    const float* W2 = (const float*)d_in[3];
    const float* b2 = (const float*)d_in[4];
    const float* W3 = (const float*)d_in[5];
    const float* b3 = (const float*)d_in[6];
    float* out = (float*)d_out;

    const size_t nx  = (size_t)B_ * IN_;
    const size_t nw1 = (size_t)T_ * IN_ * H_;

    bf16_t* xt  = (bf16_t*)d_ws;
    bf16_t* w1t = xt + nx;
    bf16_t* w2t = w1t + nw1;

    tile_all<<<dim3(T_ * KC1 + T_ * 8 + 32 * KC1), 256, 0, stream>>>(x, W1, W2, xt, w1t, w2t);
    mtmlp_fused6<<<dim3(4096), 256, 0, stream>>>(xt, w1t, b1, w2t, b2, W3, b3, out);
}